// Round 12
// baseline (243.835 us; speedup 1.0000x reference)
//
#include <hip/hip_runtime.h>

// Problem constants (from reference)
#define D0 256
#define D1 256
#define D2 256
#define NPTS 65536
#define HALF 3

// Tile decomposition: 32(x) x 16(y) x 16(z) voxels = 8192 voxels = 32 KB LDS.
#define TX 32
#define TY 16
#define TZ 16
#define NTILES 2048
#define TILE_VOX (TX * TY * TZ)     // 8192

#define BLK 512                     // 8 waves per block
#define WPB 8
#define NBLK 1024                   // fused grid: 4 blocks/CU x 256 CU, ALL co-resident
#define CAP 256                     // per-tile list capacity (measured mean ~72)
#define CSTRIDE 16                  // one counter per 64B line (r11)

// Workspace layout (int units)
#define WS_BAR    0                              // grid-barrier counter (16 ints)
#define WS_COUNTS 16                             // 2048 counters, 64B-strided
#define WS_PREP   (WS_COUNTS + NTILES * CSTRIDE) // 32784: 12 floats/point (16B-aligned)
#define WS_LIST   (WS_PREP + NPTS * 12)
#define LIST_INTS (NTILES * CAP / 2)             // ushort lists
#define FULL_INTS  (WS_LIST + LIST_INTS)         // ~4.33 MB
#define WS_LIST_NP WS_PREP
#define SMALL_INTS (WS_LIST_NP + LIST_INTS)      // ~1.18 MB

// ---------------------------------------------------------------------------
// Feasible window offsets: m = [9,4,1,0,0,1,4]; feasible iff
// m[i]+m[j]+m[k] <= 9 -> 220 of 343. Pad to 256 with (100,100,100).
// ---------------------------------------------------------------------------
struct OffTable { unsigned v[256]; };

constexpr OffTable make_table() {
    OffTable t{};
    int m[7] = {9, 4, 1, 0, 0, 1, 4};
    int n = 0;
    for (int i = 0; i < 7; i++)
        for (int j = 0; j < 7; j++)
            for (int k = 0; k < 7; k++)
                if (m[i] + m[j] + m[k] <= 9)
                    t.v[n++] = (unsigned)(i | (j << 8) | (k << 16));
    for (; n < 256; n++)
        t.v[n] = (unsigned)(100 | (100 << 8) | (100 << 16));
    return t;
}

__device__ __constant__ OffTable g_tab = make_table();

// ---------------------------------------------------------------------------
// Per-point params. FP EXPRESSIONS FROZEN (r8-r11-passing shapes).
// ---------------------------------------------------------------------------
struct PP { float fx, fy, fz, val, ix, iy, iz, D, E, F; int pack; };

template<bool PREP>
__device__ __forceinline__ PP load_pt(const float* __restrict__ paras,
                                      const float* __restrict__ prep, int pidx) {
    PP P;
    if constexpr (PREP) {
        const float4* p4 = (const float4*)prep + pidx * 3;
        float4 a = p4[0], b4 = p4[1], c4 = p4[2];
        P.fx = a.x;  P.fy = a.y;  P.fz = a.z;  P.val = a.w;
        P.ix = b4.x; P.iy = b4.y; P.iz = b4.z; P.D = b4.w;
        P.E = c4.x;  P.F = c4.y;  P.pack = __float_as_int(c4.z);
    } else {
        float px = paras[pidx], py = paras[NPTS + pidx], pz = paras[2 * NPTS + pidx];
        P.val = paras[3 * NPTS + pidx];
        float rx  = paras[4 * NPTS + pidx], rxy = paras[5 * NPTS + pidx];
        float rxz = paras[6 * NPTS + pidx], ry  = paras[7 * NPTS + pidx];
        float ryz = paras[8 * NPTS + pidx], rz  = paras[9 * NPTS + pidx];
        int cx = (int)floorf(px) - HALF;
        int cy = (int)floorf(py) - HALF;
        int cz = (int)floorf(pz) - HALF;
        P.fx = (float)cx - px; P.fy = (float)cy - py; P.fz = (float)cz - pz;
        P.ix = __fdividef(1.f, rx); P.iy = __fdividef(1.f, ry);
        P.iz = __fdividef(1.f, rz);
        P.D = rxy; P.E = rxz; P.F = ryz;
        P.pack = (cx + 8) | ((cy + 8) << 10) | ((cz + 8) << 20);
    }
    return P;
}

// ---------------------------------------------------------------------------
// FUSED kernel: bin phase -> device-scope grid barrier -> splat phase.
// 1024 blocks x 512 threads; co-residency guaranteed (32KB LDS, <=64 VGPR via
// launch_bounds, 8 waves -> exactly 4 blocks/CU). Block b owns tiles 2b, 2b+1.
// ---------------------------------------------------------------------------
template<bool PREP>
__global__ __launch_bounds__(512, 8)
void fused_splat(const float* __restrict__ paras,
                 const float* __restrict__ dist_p,
                 const float* __restrict__ thr_p,
                 int* __restrict__ ws, int list_off,
                 float* __restrict__ out) {
    __shared__ float acc[TILE_VOX];   // exactly 32 KB

    const int tid  = threadIdx.x;
    const int gtid = blockIdx.x * BLK + tid;    // 0 .. 524287 = NPTS*8

    // ---------------- bin phase (r11 body: 8 threads/point) ----------------
    {
        int p = gtid >> 3, j = gtid & 7;
        float px = paras[p], py = paras[NPTS + p], pz = paras[2 * NPTS + p];
        int cx = (int)floorf(px) - HALF;
        int cy = (int)floorf(py) - HALF;
        int cz = (int)floorf(pz) - HALF;

        if (PREP && j == 0) {
            float val = paras[3 * NPTS + p];
            float rx  = paras[4 * NPTS + p], rxy = paras[5 * NPTS + p];
            float rxz = paras[6 * NPTS + p], ry  = paras[7 * NPTS + p];
            float ryz = paras[8 * NPTS + p], rz  = paras[9 * NPTS + p];
            int pack = (cx + 8) | ((cy + 8) << 10) | ((cz + 8) << 20);
            float4* o = (float4*)(ws + WS_PREP) + p * 3;
            o[0] = make_float4((float)cx - px, (float)cy - py, (float)cz - pz, val);
            o[1] = make_float4(__fdividef(1.f, rx), __fdividef(1.f, ry),
                               __fdividef(1.f, rz), rxy);
            o[2] = make_float4(rxz, ryz, __int_as_float(pack), 0.f);
        }

        int xlo = max(cx, 0), xhi = min(cx + 6, D0 - 1);
        int ylo = max(cy, 0), yhi = min(cy + 6, D1 - 1);
        int zlo = max(cz, 0), zhi = min(cz + 6, D2 - 1);
        int txa = xlo >> 5, txb = xhi >> 5;
        int tya = ylo >> 4, tyb = yhi >> 4;
        int tza = zlo >> 4, tzb = zhi >> 4;

        bool dup = ((j & 1) && txb == txa) ||
                   ((j & 2) && tyb == tya) ||
                   ((j & 4) && tzb == tza);
        if (!dup) {
            int tx = (j & 1) ? txb : txa;
            int ty = (j & 2) ? tyb : tya;
            int tz = (j & 4) ? tzb : tza;
            int tt = (tx << 8) | (ty << 4) | tz;
            int slot = atomicAdd(&ws[WS_COUNTS + tt * CSTRIDE], 1);
            if (slot < CAP)
                ((unsigned short*)(ws + list_off))[tt * CAP + slot] = (unsigned short)p;
        }
    }

    // ---------------- grid barrier (device scope, cross-XCD) ----------------
    __syncthreads();
    if (tid == 0) {
        // release: write back this XCD's L2 (bin stores) before signaling
        __hip_atomic_fetch_add(&ws[WS_BAR], 1, __ATOMIC_ACQ_REL,
                               __HIP_MEMORY_SCOPE_AGENT);
        // acquire-spin: invalidate stale L2/L1 so bin data is visible
        while (__hip_atomic_load(&ws[WS_BAR], __ATOMIC_ACQUIRE,
                                 __HIP_MEMORY_SCOPE_AGENT) < NBLK)
            __builtin_amdgcn_s_sleep(2);
    }
    __syncthreads();

    // ---------------- splat phase (r11 body, 2 static tiles/block) ----------
    int   oiv[4], ojv[4], okv[4];
    float foi[4], foj[4], fok[4];
    const int lane = tid & 63, wid = tid >> 6;
#pragma unroll
    for (int t = 0; t < 4; t++) {
        unsigned pk = g_tab.v[t * 64 + lane];
        oiv[t] = pk & 255; ojv[t] = (pk >> 8) & 255; okv[t] = (int)(pk >> 16);
        foi[t] = (float)oiv[t]; foj[t] = (float)ojv[t]; fok[t] = (float)okv[t];
    }

    const float dist  = dist_p[0];
    const float thr   = thr_p[0];
    const float d2max = dist * dist;
    float4* acc4 = (float4*)acc;

    for (int rep = 0; rep < 2; rep++) {
        const int b = (blockIdx.x << 1) | rep;
        const int tzi = b & 15, tyi = (b >> 4) & 15, txi = b >> 8;
        const int X0 = txi * TX, Y0 = tyi * TY, Z0 = tzi * TZ;

        for (int q = tid; q < TILE_VOX / 4; q += BLK)
            acc4[q] = make_float4(0.f, 0.f, 0.f, 0.f);
        __syncthreads();

        const int n = min(ws[WS_COUNTS + b * CSTRIDE], CAP);
        const unsigned short* list =
            (const unsigned short*)(ws + list_off) + b * CAP;

        int i = wid;
        PP cur;
        if (i < n) {
            int pidx = __builtin_amdgcn_readfirstlane((int)list[i]);
            cur = load_pt<PREP>(paras, (const float*)(ws + WS_PREP), pidx);
        }
        while (i < n) {
            int inext = i + WPB;
            PP nxt = cur;
            if (inext < n) {
                int pidx2 = __builtin_amdgcn_readfirstlane((int)list[inext]);
                nxt = load_pt<PREP>(paras, (const float*)(ws + WS_PREP), pidx2);
            }

            int pk  = cur.pack;
            int vx0 = (pk & 1023) - 8 - X0;
            int vy0 = ((pk >> 10) & 1023) - 8 - Y0;
            int vz0 = (pk >> 20) - 8 - Z0;

#pragma unroll
            for (int t = 0; t < 4; t++) {
                int vx = vx0 + oiv[t], vy = vy0 + ojv[t], vz = vz0 + okv[t];
                float dx = cur.fx + foi[t];
                float dy = cur.fy + foj[t];
                float dz = cur.fz + fok[t];
                // FROZEN: plain form, compiler-contracted
                float d2 = dx * dx + dy * dy + dz * dz;

                bool pass = ((unsigned)vx < (unsigned)TX) &
                            ((unsigned)vy < (unsigned)TY) &
                            ((unsigned)vz < (unsigned)TZ) &
                            (d2 <= d2max);
                if (pass) {
                    float ax = dx * cur.ix, ay = dy * cur.iy, az = dz * cur.iz;
                    float q = ax * ax + ay * ay + az * az
                            + cur.D * dx * dy + cur.E * dx * dz + cur.F * dy * dz;
                    float w = __expf(-0.5f * q);
                    if (w > thr)
                        atomicAdd(&acc[(vx << 8) | (vy << 4) | vz], cur.val * w);
                }
            }
            cur = nxt;
            i = inext;
        }
        __syncthreads();

        for (int q = tid; q < TILE_VOX / 4; q += BLK) {
            int vz = (q & 3) << 2;
            int vy = (q >> 2) & 15;
            int vx = q >> 6;
            *(float4*)&out[((X0 + vx) * D1 + (Y0 + vy)) * D2 + Z0 + vz] = acc4[q];
        }
        __syncthreads();   // acc reused next rep
    }
}

// ---------------------------------------------------------------------------
// Fallback (tiny ws): scatter with global atomics.
// ---------------------------------------------------------------------------
__global__ __launch_bounds__(256)
void zero_kernel(float4* __restrict__ out, int n4) {
    int i = blockIdx.x * blockDim.x + threadIdx.x;
    int stride = gridDim.x * blockDim.x;
    for (; i < n4; i += stride)
        out[i] = make_float4(0.f, 0.f, 0.f, 0.f);
}

__global__ __launch_bounds__(256)
void splat_fallback(const float* __restrict__ paras,
                    const float* __restrict__ dist_p,
                    const float* __restrict__ thr_p,
                    float* __restrict__ out) {
    int wave = (blockIdx.x * blockDim.x + threadIdx.x) >> 6;
    int lane = threadIdx.x & 63;
    int p = __builtin_amdgcn_readfirstlane(wave);

    const int N = NPTS;
    float px  = paras[0 * N + p], py  = paras[1 * N + p], pz  = paras[2 * N + p];
    float val = paras[3 * N + p];
    float rx  = paras[4 * N + p], rxy = paras[5 * N + p], rxz = paras[6 * N + p];
    float ry  = paras[7 * N + p], ryz = paras[8 * N + p], rz  = paras[9 * N + p];

    float dist = dist_p[0], thr = thr_p[0];
    float d2max = dist * dist;

    int cx = (int)floorf(px) - HALF;
    int cy = (int)floorf(py) - HALF;
    int cz = (int)floorf(pz) - HALF;
    float fx = (float)cx - px, fy = (float)cy - py, fz = (float)cz - pz;
    float irx = __fdividef(1.f, rx), iry = __fdividef(1.f, ry),
          irz = __fdividef(1.f, rz);

#pragma unroll
    for (int t = 0; t < 4; t++) {
        unsigned pk = g_tab.v[t * 64 + lane];
        int oi = pk & 255, oj = (pk >> 8) & 255, ok = pk >> 16;
        int vx = cx + oi, vy = cy + oj, vz = cz + ok;
        float dx = fx + (float)oi, dy = fy + (float)oj, dz = fz + (float)ok;
        float d2 = dx * dx + dy * dy + dz * dz;
        bool inb = ((unsigned)vx < (unsigned)D0) &
                   ((unsigned)vy < (unsigned)D1) &
                   ((unsigned)vz < (unsigned)D2);
        if (inb && d2 <= d2max) {
            float ax = dx * irx, ay = dy * iry, az = dz * irz;
            float q = ax * ax + ay * ay + az * az
                    + rxy * dx * dy + rxz * dx * dz + ryz * dy * dz;
            float w = __expf(-0.5f * q);
            if (w > thr)
                atomicAdd(&out[(vx << 16) + (vy << 8) + vz], val * w);
        }
    }
}

extern "C" void kernel_launch(void* const* d_in, const int* in_sizes, int n_in,
                              void* d_out, int out_size, void* d_ws, size_t ws_size,
                              hipStream_t stream) {
    const float* paras  = (const float*)d_in[0];
    const float* dist_p = (const float*)d_in[1];
    const float* thr_p  = (const float*)d_in[2];
    float* out = (float*)d_out;
    int* ws = (int*)d_ws;

    if (ws_size >= (size_t)FULL_INTS * 4) {
        // zero barrier + counters (132 KB) in one node, then ONE fused kernel
        hipMemsetAsync(ws, 0, (size_t)(WS_COUNTS + NTILES * CSTRIDE) * 4, stream);
        fused_splat<true><<<NBLK, BLK, 0, stream>>>(paras, dist_p, thr_p,
                                                    ws, WS_LIST, out);
    } else if (ws_size >= (size_t)SMALL_INTS * 4) {
        hipMemsetAsync(ws, 0, (size_t)(WS_COUNTS + NTILES * CSTRIDE) * 4, stream);
        fused_splat<false><<<NBLK, BLK, 0, stream>>>(paras, dist_p, thr_p,
                                                     ws, WS_LIST_NP, out);
    } else {
        zero_kernel<<<4096, 256, 0, stream>>>((float4*)out, out_size / 4);
        splat_fallback<<<NPTS / 4, 256, 0, stream>>>(paras, dist_p, thr_p, out);
    }
}

// Round 13
// 179.273 us; speedup vs baseline: 1.3601x; 1.3601x over previous
//
#include <hip/hip_runtime.h>

// Problem constants (from reference)
#define D0 256
#define D1 256
#define D2 256
#define NPTS 65536
#define HALF 3

// Tile decomposition: 32(x) x 16(y) x 16(z) voxels = 8192 voxels = 32 KB LDS.
#define TX 32
#define TY 16
#define TZ 16
#define NTILES 2048
#define TILE_VOX (TX * TY * TZ)     // 8192

#define BLK 512                     // 8 waves per block
#define PTS_PER_WAVE (NPTS / 8)     // each of 8 waves scans 8192 points

// Workspace layout (int units): NO counters, NO lists, NO memset needed.
#define WS_HOME   0                          // 65536 packed home ints (dense)
#define WS_PREP   NPTS                       // 12 floats/point, 16B aligned
#define FULL_INTS (NPTS + NPTS * 12)         // 3.4 MB

// ---------------------------------------------------------------------------
// Feasible window offsets: m = [9,4,1,0,0,1,4]; feasible iff
// m[i]+m[j]+m[k] <= 9 -> 220 of 343. Pad to 256 with (100,100,100).
// ---------------------------------------------------------------------------
struct OffTable { unsigned v[256]; };

constexpr OffTable make_table() {
    OffTable t{};
    int m[7] = {9, 4, 1, 0, 0, 1, 4};
    int n = 0;
    for (int i = 0; i < 7; i++)
        for (int j = 0; j < 7; j++)
            for (int k = 0; k < 7; k++)
                if (m[i] + m[j] + m[k] <= 9)
                    t.v[n++] = (unsigned)(i | (j << 8) | (k << 16));
    for (; n < 256; n++)
        t.v[n] = (unsigned)(100 | (100 << 8) | (100 << 16));
    return t;
}

__device__ __constant__ OffTable g_tab = make_table();

// ---------------------------------------------------------------------------
// Per-point params. FP EXPRESSIONS FROZEN (r8-r12-passing shapes) — masks sit
// on rounding boundaries vs the harness's np ref; only structure changes.
// ---------------------------------------------------------------------------
struct PP { float fx, fy, fz, val, ix, iy, iz, D, E, F; int pack; };

__device__ __forceinline__ PP load_pt(const float* __restrict__ prep, int pidx) {
    PP P;
    const float4* p4 = (const float4*)prep + pidx * 3;
    float4 a = p4[0], b4 = p4[1], c4 = p4[2];
    P.fx = a.x;  P.fy = a.y;  P.fz = a.z;  P.val = a.w;
    P.ix = b4.x; P.iy = b4.y; P.iz = b4.z; P.D = b4.w;
    P.E = c4.x;  P.F = c4.y;  P.pack = __float_as_int(c4.z);
    return P;
}

// ---------------------------------------------------------------------------
// Prep: one thread per point, NO atomics. Writes dense packed-home int and
// the 48B PP record. (pack = (cx+8) | (cy+8)<<10 | (cz+8)<<20)
// ---------------------------------------------------------------------------
__global__ __launch_bounds__(256)
void prep_kernel(const float* __restrict__ paras, int* __restrict__ ws) {
    int p = blockIdx.x * 256 + threadIdx.x;
    float px = paras[p], py = paras[NPTS + p], pz = paras[2 * NPTS + p];
    int cx = (int)floorf(px) - HALF;
    int cy = (int)floorf(py) - HALF;
    int cz = (int)floorf(pz) - HALF;

    float val = paras[3 * NPTS + p];
    float rx  = paras[4 * NPTS + p], rxy = paras[5 * NPTS + p];
    float rxz = paras[6 * NPTS + p], ry  = paras[7 * NPTS + p];
    float ryz = paras[8 * NPTS + p], rz  = paras[9 * NPTS + p];
    int pack = (cx + 8) | ((cy + 8) << 10) | ((cz + 8) << 20);

    ws[WS_HOME + p] = pack;
    float4* o = (float4*)(ws + WS_PREP) + p * 3;
    o[0] = make_float4((float)cx - px, (float)cy - py, (float)cz - pz, val);
    o[1] = make_float4(__fdividef(1.f, rx), __fdividef(1.f, ry),
                       __fdividef(1.f, rz), rxy);
    o[2] = make_float4(rxz, ryz, __int_as_float(pack), 0.f);
}

// ---------------------------------------------------------------------------
// Scan-splat: one block per tile. Each of 8 waves scans its 8192-point strip
// of the dense home[] array (L2-resident), ballots overlap hits (~72/block
// total), and processes each hit wave-wide with the frozen splat body into
// LDS acc. No global atomics anywhere. Coalesced float4 writeout.
// ---------------------------------------------------------------------------
__global__ __launch_bounds__(512)
void scan_splat(const float* __restrict__ dist_p,
                const float* __restrict__ thr_p,
                const int* __restrict__ ws,
                float* __restrict__ out) {
    __shared__ float acc[TILE_VOX];   // exactly 32 KB

    const int b   = blockIdx.x;
    const int tzi = b & 15, tyi = (b >> 4) & 15, txi = b >> 8;
    const int X0 = txi * TX, Y0 = tyi * TY, Z0 = tzi * TZ;
    const int tid = threadIdx.x;
    const int wid = tid >> 6, lane = tid & 63;

    // Per-lane window offsets (hoisted).
    int   oiv[4], ojv[4], okv[4];
    float foi[4], foj[4], fok[4];
#pragma unroll
    for (int t = 0; t < 4; t++) {
        unsigned pk = g_tab.v[t * 64 + lane];
        oiv[t] = pk & 255; ojv[t] = (pk >> 8) & 255; okv[t] = (int)(pk >> 16);
        foi[t] = (float)oiv[t]; foj[t] = (float)ojv[t]; fok[t] = (float)okv[t];
    }

    float4* acc4 = (float4*)acc;
    for (int q = tid; q < TILE_VOX / 4; q += BLK)
        acc4[q] = make_float4(0.f, 0.f, 0.f, 0.f);
    __syncthreads();

    const float dist  = dist_p[0];
    const float thr   = thr_p[0];
    const float d2max = dist * dist;
    const float* prep = (const float*)(ws + WS_PREP);
    const int* home = ws + WS_HOME;

    // Overlap test constants: point touches this tile iff
    //   cx in [X0-6, X0+31]  ->  (cx+8) - (X0+2)  in [0, 37]
    //   cy in [Y0-6, Y0+15]  ->  (cy+8) - (Y0+2)  in [0, 21]
    //   cz in [Z0-6, Z0+15]  ->  (cz+8) - (Z0+2)  in [0, 21]
    const int bx = X0 + 2, by = Y0 + 2, bz = Z0 + 2;

    const int wstart = wid * PTS_PER_WAVE;
    for (int it = 0; it < PTS_PER_WAVE; it += 64) {
        const int wbase = wstart + it;
        int hp = home[wbase + lane];
        bool hit = ((unsigned)((hp & 1023) - bx) <= 37u) &
                   ((unsigned)(((hp >> 10) & 1023) - by) <= 21u) &
                   ((unsigned)((hp >> 20) - bz) <= 21u);

        unsigned long long m = __ballot(hit);
        while (m) {
            int l = __ffsll(m) - 1;
            m &= m - 1;
            int pidx = __builtin_amdgcn_readfirstlane(wbase + l);
            PP cur = load_pt(prep, pidx);

            int pk  = cur.pack;
            int vx0 = (pk & 1023) - 8 - X0;
            int vy0 = ((pk >> 10) & 1023) - 8 - Y0;
            int vz0 = (pk >> 20) - 8 - Z0;

#pragma unroll
            for (int t = 0; t < 4; t++) {
                int vx = vx0 + oiv[t], vy = vy0 + ojv[t], vz = vz0 + okv[t];
                float dx = cur.fx + foi[t];
                float dy = cur.fy + foj[t];
                float dz = cur.fz + fok[t];
                // FROZEN: plain form, compiler-contracted
                float d2 = dx * dx + dy * dy + dz * dz;

                bool pass = ((unsigned)vx < (unsigned)TX) &
                            ((unsigned)vy < (unsigned)TY) &
                            ((unsigned)vz < (unsigned)TZ) &
                            (d2 <= d2max);
                if (pass) {
                    float ax = dx * cur.ix, ay = dy * cur.iy, az = dz * cur.iz;
                    float q = ax * ax + ay * ay + az * az
                            + cur.D * dx * dy + cur.E * dx * dz + cur.F * dy * dz;
                    float w = __expf(-0.5f * q);
                    if (w > thr)
                        atomicAdd(&acc[(vx << 8) | (vy << 4) | vz], cur.val * w);
                }
            }
        }
    }
    __syncthreads();

    // Coalesced float4 writeout (z fastest).
    for (int q = tid; q < TILE_VOX / 4; q += BLK) {
        int vz = (q & 3) << 2;
        int vy = (q >> 2) & 15;
        int vx = q >> 6;
        *(float4*)&out[((X0 + vx) * D1 + (Y0 + vy)) * D2 + Z0 + vz] = acc4[q];
    }
}

// ---------------------------------------------------------------------------
// Fallback (tiny ws): scatter with global atomics.
// ---------------------------------------------------------------------------
__global__ __launch_bounds__(256)
void zero_kernel(float4* __restrict__ out, int n4) {
    int i = blockIdx.x * blockDim.x + threadIdx.x;
    int stride = gridDim.x * blockDim.x;
    for (; i < n4; i += stride)
        out[i] = make_float4(0.f, 0.f, 0.f, 0.f);
}

__global__ __launch_bounds__(256)
void splat_fallback(const float* __restrict__ paras,
                    const float* __restrict__ dist_p,
                    const float* __restrict__ thr_p,
                    float* __restrict__ out) {
    int wave = (blockIdx.x * blockDim.x + threadIdx.x) >> 6;
    int lane = threadIdx.x & 63;
    int p = __builtin_amdgcn_readfirstlane(wave);

    const int N = NPTS;
    float px  = paras[0 * N + p], py  = paras[1 * N + p], pz  = paras[2 * N + p];
    float val = paras[3 * N + p];
    float rx  = paras[4 * N + p], rxy = paras[5 * N + p], rxz = paras[6 * N + p];
    float ry  = paras[7 * N + p], ryz = paras[8 * N + p], rz  = paras[9 * N + p];

    float dist = dist_p[0], thr = thr_p[0];
    float d2max = dist * dist;

    int cx = (int)floorf(px) - HALF;
    int cy = (int)floorf(py) - HALF;
    int cz = (int)floorf(pz) - HALF;
    float fx = (float)cx - px, fy = (float)cy - py, fz = (float)cz - pz;
    float irx = __fdividef(1.f, rx), iry = __fdividef(1.f, ry),
          irz = __fdividef(1.f, rz);

#pragma unroll
    for (int t = 0; t < 4; t++) {
        unsigned pk = g_tab.v[t * 64 + lane];
        int oi = pk & 255, oj = (pk >> 8) & 255, ok = pk >> 16;
        int vx = cx + oi, vy = cy + oj, vz = cz + ok;
        float dx = fx + (float)oi, dy = fy + (float)oj, dz = fz + (float)ok;
        float d2 = dx * dx + dy * dy + dz * dz;
        bool inb = ((unsigned)vx < (unsigned)D0) &
                   ((unsigned)vy < (unsigned)D1) &
                   ((unsigned)vz < (unsigned)D2);
        if (inb && d2 <= d2max) {
            float ax = dx * irx, ay = dy * iry, az = dz * irz;
            float q = ax * ax + ay * ay + az * az
                    + rxy * dx * dy + rxz * dx * dz + ryz * dy * dz;
            float w = __expf(-0.5f * q);
            if (w > thr)
                atomicAdd(&out[(vx << 16) + (vy << 8) + vz], val * w);
        }
    }
}

extern "C" void kernel_launch(void* const* d_in, const int* in_sizes, int n_in,
                              void* d_out, int out_size, void* d_ws, size_t ws_size,
                              hipStream_t stream) {
    const float* paras  = (const float*)d_in[0];
    const float* dist_p = (const float*)d_in[1];
    const float* thr_p  = (const float*)d_in[2];
    float* out = (float*)d_out;
    int* ws = (int*)d_ws;

    if (ws_size >= (size_t)FULL_INTS * 4) {
        // No memset, no atomics: prep writes dense home[] + PP records,
        // scan_splat pulls per-tile hits by scanning home[] (L2-resident).
        prep_kernel<<<NPTS / 256, 256, 0, stream>>>(paras, ws);
        scan_splat<<<NTILES, BLK, 0, stream>>>(dist_p, thr_p, ws, out);
    } else {
        zero_kernel<<<4096, 256, 0, stream>>>((float4*)out, out_size / 4);
        splat_fallback<<<NPTS / 4, 256, 0, stream>>>(paras, dist_p, thr_p, out);
    }
}